// Round 10
// baseline (101.083 us; speedup 1.0000x reference)
//
#include <hip/hip_runtime.h>
#include <hip/hip_bf16.h>
#include <math.h>

#define TOK 16384
#define HDIM 2048
#define NE 64
#define NB 4
#define KTOP 8
#define KC2 128
#define NSTEP (HDIM / KC2)   // 16 steps, 2 x 24KB W-chunks per step
#define NCH 32               // 24KB chunks in wpk
#define BT 64                // tokens per block

typedef __attribute__((ext_vector_type(8))) __bf16 bf16x8;
typedef __attribute__((ext_vector_type(4))) float f32x4;
typedef unsigned int uint;

__device__ __forceinline__ uint asu(float f) { union { float f; uint u; } c; c.f = f; return c.u; }
__device__ __forceinline__ float asf(uint u) { union { uint u; float f; } c; c.u = u; return c.f; }

// Exact 3-way bf16 split: h+m+l == x bitwise (8 mantissa bits per plane).
__device__ __forceinline__ void split3(float v, uint& h, uint& m, uint& l) {
  uint u = asu(v);
  h = u & 0xffff0000u;
  float d = v - asf(h);
  m = asu(d) & 0xffff0000u;
  float d2 = d - asf(m);
  l = asu(d2);
}

// 8 floats (one fragment k-slot) -> 3 bf16x8 planes, in-register.
__device__ __forceinline__ void split8(float4 a, float4 b,
                                       bf16x8& h8, bf16x8& m8, bf16x8& l8) {
  union { uint4 u; bf16x8 v; } H, M, L;
  uint h0, m0, l0, h1, m1, l1;
  split3(a.x, h0, m0, l0); split3(a.y, h1, m1, l1);
  H.u.x = (h0 >> 16) | (h1 & 0xffff0000u);
  M.u.x = (m0 >> 16) | (m1 & 0xffff0000u);
  L.u.x = (l0 >> 16) | (l1 & 0xffff0000u);
  split3(a.z, h0, m0, l0); split3(a.w, h1, m1, l1);
  H.u.y = (h0 >> 16) | (h1 & 0xffff0000u);
  M.u.y = (m0 >> 16) | (m1 & 0xffff0000u);
  L.u.y = (l0 >> 16) | (l1 & 0xffff0000u);
  split3(b.x, h0, m0, l0); split3(b.y, h1, m1, l1);
  H.u.z = (h0 >> 16) | (h1 & 0xffff0000u);
  M.u.z = (m0 >> 16) | (m1 & 0xffff0000u);
  L.u.z = (l0 >> 16) | (l1 & 0xffff0000u);
  split3(b.z, h0, m0, l0); split3(b.w, h1, m1, l1);
  H.u.w = (h0 >> 16) | (h1 & 0xffff0000u);
  M.u.w = (m0 >> 16) | (m1 & 0xffff0000u);
  L.u.w = (l0 >> 16) | (l1 & 0xffff0000u);
  h8 = H.v; m8 = M.v; l8 = L.v;
}

__device__ __forceinline__ void gl_lds16(const void* g, void* l) {
  __builtin_amdgcn_global_load_lds(
      (const __attribute__((address_space(1))) void*)g,
      (__attribute__((address_space(3))) void*)l, 16, 0, 0);
}

// ---------------------------------------------------------------------------
// wsplit: pack W into B-fragment order, 3 exact bf16 planes; zero stats.
// byte addr = c*24576 + ks*12288 + half*6144 + f2*3072 + plane*1024 + lane*16
// Fragment (c,ks,half,f2,plane,lane): e = half*32+f2*16+(lane&15),
//                                     k = c*64+ks*32+(lane>>4)*8
// ---------------------------------------------------------------------------
__global__ __launch_bounds__(256) void wsplit(const float* __restrict__ w,
                                              char* __restrict__ wpk,
                                              float* __restrict__ stats) {
  if (blockIdx.x == 0 && threadIdx.x < 132) {   // zero ce+ssum+cnt (528 floats)
    *(float4*)(stats + threadIdx.x * 4) = make_float4(0.f, 0.f, 0.f, 0.f);
  }
  int t = blockIdx.x * 256 + threadIdx.x;    // 16384 threads
  int lane = t & 63;
  int f2 = (t >> 6) & 1, half = (t >> 7) & 1, ks = (t >> 8) & 1, c = t >> 9;
  int e = half * 32 + f2 * 16 + (lane & 15);
  int k = c * 64 + ks * 32 + ((lane >> 4) << 3);
  const float* p = w + (size_t)e * HDIM + k;
  bf16x8 h8, m8, l8;
  split8(*(const float4*)p, *(const float4*)(p + 4), h8, m8, l8);
  union { bf16x8 v; uint4 u; } H, M, L;
  H.v = h8; M.v = m8; L.v = l8;
  size_t base = (size_t)c * 24576 + (size_t)ks * 12288 + (size_t)half * 6144
              + (size_t)f2 * 3072 + (size_t)lane * 16;
  *(uint4*)(wpk + base) = H.u;
  *(uint4*)(wpk + base + 1024) = M.u;
  *(uint4*)(wpk + base + 2048) = L.u;
}

// ---------------------------------------------------------------------------
// Fused gate. 256 blocks x 512 thr (8 waves), 1 block/CU.
// Wave = 16 tokens x 32 experts (2 C-frags); block = 64 tok x 64 exp.
// K-STEP = 128 (2 chunks) -> 16 sync steps instead of 32: the measured
// ~2000-2800 cy per-step constant (drain+barrier+queueing, invariant across
// r4/r6/r8/r9 structures) is paid half as often, and per-step compute
// (~2144 cy/SIMD) now exceeds it.
//   X: global->reg (plain float4, r4-proven), prefetch next step during this.
//   W: gl_lds into 2 x 48KB LDS dbuf.
// One vmcnt(0)+barrier per step. gate_final folded in via completion counter.
// ---------------------------------------------------------------------------
__global__ __launch_bounds__(512, 2) void gate_fused(const float* __restrict__ x,
                                                     const char* __restrict__ wpk,
                                                     float* __restrict__ out,
                                                     float* __restrict__ ce,
                                                     float* __restrict__ ssum,
                                                     int* __restrict__ cnt) {
  __shared__ __align__(16) char lds[98304];   // W dbuf: 2 x 48 KB
  __shared__ float hist[NE];
  __shared__ int lastflag;

  const int tid = threadIdx.x;
  const int bid = blockIdx.x;
  const int t0 = bid * BT;
  const int b = bid >> 6;                     // 64 blocks per batch row
  const int lane = tid & 63;
  const int wid = tid >> 6;                   // 0..7
  const int half = wid & 1;                   // expert half
  const int tg = (wid >> 1);                  // token group 0..3 (16 tok each)

  if (tid < NE) hist[tid] = 0.f;

  // per-lane X base: row = t0+tg*16+(lane&15), k-slot offset (lane>>4)*8
  const float* xrow = x + (size_t)(t0 + tg * 16 + (lane & 15)) * HDIM + ((lane >> 4) << 3);
  const char* wsrc = wpk + (size_t)lane * 16;

  f32x4 acc[2] = {{0.f, 0.f, 0.f, 0.f}, {0.f, 0.f, 0.f, 0.f}};
  float4 XA[8], XB[8];

#define STAGE_W(s, sel)                                                       \
  {                                                                           \
    const char* wp_ = wsrc + (size_t)(s) * 49152;                             \
    char* wd_ = lds + (sel) * 49152;                                          \
    _Pragma("unroll")                                                         \
    for (int i = 0; i < 6; ++i)                                               \
      gl_lds16(wp_ + (i * 8 + wid) * 1024, wd_ + (i * 8 + wid) * 1024);       \
  }

#define LOADX(XP, s)                                                          \
  {                                                                           \
    const float* xp_ = xrow + (size_t)(s) * KC2;                              \
    XP[0] = *(const float4*)(xp_);                                            \
    XP[1] = *(const float4*)(xp_ + 4);                                        \
    XP[2] = *(const float4*)(xp_ + 32);                                       \
    XP[3] = *(const float4*)(xp_ + 36);                                       \
    XP[4] = *(const float4*)(xp_ + 64);                                       \
    XP[5] = *(const float4*)(xp_ + 68);                                       \
    XP[6] = *(const float4*)(xp_ + 96);                                       \
    XP[7] = *(const float4*)(xp_ + 100);                                      \
  }

#define STEP(s, XU, XP)                                                       \
  {                                                                           \
    if ((s) + 1 < NSTEP) {                                                    \
      STAGE_W((s) + 1, ((s) + 1) & 1);      /* stage next step's W (async) */ \
      LOADX(XP, (s) + 1);                   /* prefetch next step's X */      \
    }                                                                         \
    _Pragma("unroll")                                                         \
    for (int h = 0; h < 2; ++h) {                                             \
      _Pragma("unroll")                                                       \
      for (int ks = 0; ks < 2; ++ks) {                                        \
        bf16x8 ah, am, al;                                                    \
        split8(XU[h * 4 + ks * 2], XU[h * 4 + ks * 2 + 1], ah, am, al);       \
        const char* wk = lds + ((s) & 1) * 49152 + h * 24576 + ks * 12288     \
                       + half * 6144 + lane * 16;                             \
        _Pragma("unroll")                                                     \
        for (int f2 = 0; f2 < 2; ++f2) {                                      \
          const char* bb = wk + f2 * 3072;                                    \
          bf16x8 bh = *(const bf16x8*)(bb);                                   \
          bf16x8 bm = *(const bf16x8*)(bb + 1024);                            \
          bf16x8 bl = *(const bf16x8*)(bb + 2048);                            \
          acc[f2] = __builtin_amdgcn_mfma_f32_16x16x32_bf16(ah, bh, acc[f2], 0, 0, 0); \
          acc[f2] = __builtin_amdgcn_mfma_f32_16x16x32_bf16(ah, bm, acc[f2], 0, 0, 0); \
          acc[f2] = __builtin_amdgcn_mfma_f32_16x16x32_bf16(am, bh, acc[f2], 0, 0, 0); \
          acc[f2] = __builtin_amdgcn_mfma_f32_16x16x32_bf16(ah, bl, acc[f2], 0, 0, 0); \
          acc[f2] = __builtin_amdgcn_mfma_f32_16x16x32_bf16(al, bh, acc[f2], 0, 0, 0); \
          acc[f2] = __builtin_amdgcn_mfma_f32_16x16x32_bf16(am, bm, acc[f2], 0, 0, 0); \
        }                                                                     \
      }                                                                       \
    }                                                                         \
    asm volatile("s_waitcnt vmcnt(0)" ::: "memory");                          \
    __builtin_amdgcn_s_barrier();                                             \
    asm volatile("" ::: "memory");                                            \
  }

  // ---- prologue: W(step0) + X(step0); drain; barrier
  STAGE_W(0, 0);
  LOADX(XA, 0);
  asm volatile("s_waitcnt vmcnt(0)" ::: "memory");
  __builtin_amdgcn_s_barrier();
  asm volatile("" ::: "memory");

#pragma unroll 1
  for (int ss = 0; ss < NSTEP; ss += 2) {
    STEP(ss, XA, XB);
    STEP(ss + 1, XB, XA);
  }
#undef STEP
#undef STAGE_W
#undef LOADX

  // C frags -> sc[expert][token]. C layout: col(=expert)=lane&15,
  // row(=token)=(lane>>4)*4+reg  [m89-verified]
  float (*sc)[BT + 1] = (float(*)[BT + 1])lds;
#pragma unroll
  for (int f2 = 0; f2 < 2; ++f2) {
    int e = half * 32 + f2 * 16 + (lane & 15);
    int tk = tg * 16 + ((lane >> 4) << 2);
    sc[e][tk + 0] = acc[f2][0];
    sc[e][tk + 1] = acc[f2][1];
    sc[e][tk + 2] = acc[f2][2];
    sc[e][tk + 3] = acc[f2][3];
  }
  __syncthreads();

  // softmax + top-8: 8 lanes per token (t = 0..63), 8 experts per lane
  const int t = tid >> 3;
  const int j = tid & 7;
  float p[8];
#pragma unroll
  for (int i = 0; i < 8; ++i) p[i] = sc[j * 8 + i][t];

  float m = p[0];
#pragma unroll
  for (int i = 1; i < 8; ++i) m = fmaxf(m, p[i]);
  m = fmaxf(m, __shfl_xor(m, 1, 8));
  m = fmaxf(m, __shfl_xor(m, 2, 8));
  m = fmaxf(m, __shfl_xor(m, 4, 8));
  float s = 0.f;
#pragma unroll
  for (int i = 0; i < 8; ++i) { p[i] = __expf(p[i] - m); s += p[i]; }
  s += __shfl_xor(s, 1, 8);
  s += __shfl_xor(s, 2, 8);
  s += __shfl_xor(s, 4, 8);
  float inv = 1.f / s;
#pragma unroll
  for (int i = 0; i < 8; ++i) { p[i] *= inv; sc[j * 8 + i][t] = p[i]; }

  // top-8: strict-> scan (lowest idx on tie), 8-lane (val,idx) reduce
  unsigned used = 0;
  float wsum = 0.f;
  float wv[KTOP];
  int wi_[KTOP];
#pragma unroll
  for (int sel = 0; sel < KTOP; ++sel) {
    float bv = -1.f;
    int bi = 0;
#pragma unroll
    for (int i = 0; i < 8; ++i) {
      bool ok = !((used >> i) & 1u);
      if (ok && p[i] > bv) { bv = p[i]; bi = i; }
    }
    int ge = j * 8 + bi;
#pragma unroll
    for (int mk = 1; mk < 8; mk <<= 1) {
      float ov = __shfl_xor(bv, mk, 8);
      int og = __shfl_xor(ge, mk, 8);
      if (ov > bv || (ov == bv && og < ge)) { bv = ov; ge = og; }
    }
    if ((ge >> 3) == j) used |= 1u << (ge & 7);
    wv[sel] = bv;
    wi_[sel] = ge;
    wsum += bv;
  }
  if (j == 0) {
    float winv = 1.f / (wsum + 1e-20f);
#pragma unroll
    for (int sel = 0; sel < KTOP; ++sel) {
      out[(size_t)(t0 + t) * KTOP + sel] = (float)wi_[sel];
      out[(size_t)TOK * KTOP + (size_t)(t0 + t) * KTOP + sel] = wv[sel] * winv;
      atomicAdd(&hist[wi_[sel]], 1.f);
    }
  }
  __syncthreads();

  if (tid < NE) {
    float ssl = 0.f;
#pragma unroll
    for (int tt = 0; tt < BT; ++tt) ssl += sc[tid][tt];
    atomicAdd(&ssum[b * NE + tid], ssl);
    atomicAdd(&ce[b * NE + tid], hist[tid]);
  }

  // ---- merged finalize: last block to finish computes loads + aux_loss.
  // ce/ssum atomics (L2, device-scope) are ordered before the counter bump by
  // the threadfence; this block never read ce/ssum -> L1-fresh reads from L2.
  __threadfence();
  __syncthreads();
  if (tid == 0) lastflag = (atomicAdd(cnt, 1) == gridDim.x - 1);
  __syncthreads();
  if (lastflag && tid < 64) {
    const int e = tid;
    float loads = 0.f, aux = 0.f;
#pragma unroll
    for (int b2 = 0; b2 < NB; ++b2) {
      float c = ce[b2 * 64 + e];
      loads += c;
      aux += (c / 512.0f) * (ssum[b2 * 64 + e] / 4096.0f);  // (S*K/E), S
    }
    out[(size_t)2 * TOK * KTOP + 1 + e] = loads;
#pragma unroll
    for (int off = 32; off > 0; off >>= 1) aux += __shfl_down(aux, off);
    if (e == 0) out[(size_t)2 * TOK * KTOP] = aux * (0.1f / 4.0f);  // ALPHA/B
  }
}

extern "C" void kernel_launch(void* const* d_in, const int* in_sizes, int n_in,
                              void* d_out, int out_size, void* d_ws, size_t ws_size,
                              hipStream_t stream) {
  const float* x = (const float*)d_in[0];
  const float* w = (const float*)d_in[1];
  float* out = (float*)d_out;

  char* wpk = (char*)d_ws;                          // 32 chunks x 24 KB = 768 KB
  float* ce = (float*)(wpk + (size_t)NCH * 24576);  // [NB][NE]
  float* ssum = ce + NB * NE;                       // [NB][NE]
  int* cnt = (int*)(ssum + NB * NE);                // completion counter

  wsplit<<<dim3(64), dim3(256), 0, stream>>>(w, wpk, ce);
  gate_fused<<<dim3(TOK / BT), dim3(512), 0, stream>>>(x, wpk, out, ce, ssum, cnt);
}